// Round 4
// baseline (182.053 us; speedup 1.0000x reference)
//
#include <hip/hip_runtime.h>
#include <cstdint>
#include <cstddef>

// ---------------------------------------------------------------------------
// x = mean_i( softmax(q_i K^T / 16) ) @ h   with q = h@Wq, k = h@Wk
//   = sum_j c_j h_j,  c_j = (1/N) sum_i exp(e_ij)/l_i,  l_i = sum_j exp(e_ij)
//
// Round 4: pass kernels are barrier-free and LDS-free. R3 post-mortem showed
// the LDS port was the structural floor (~24 us/pass at 50% efficiency); k is
// L2-resident (512 KB/XCD after swizzle) so B-fragments are loaded straight
// from global (coalesced lane-linear dwordx4) into ping-pong quarter-buffers,
// interleaved with MFMA via vmcnt. 2 rowtiles/wave halve loads per MFMA.
// Floor: max(MFMA 13.8us, VALU ~11us, L2 feed ~15us) ~= 15-20 us/pass.
//
// ws: [0,4MB) q bf16 frag-major | [4MB,8MB) k frag-major | l fp32[8192] | c fp32[8192]
// Frag-major (32x32 MFMA A/B-operand layout): elem (i,d) -> tile i>>5,
//   slot (d>>4)*64 + (i&31) + 32*((d>>3)&1), byte j = d&7.
//   One 32-row tile = 16 KB contiguous; dword index within tile = a0*64+lane.
// ---------------------------------------------------------------------------

#define N_ROWS 8192
#define DIM    256

typedef __bf16 bf16x8 __attribute__((ext_vector_type(8)));
typedef unsigned short u16x8 __attribute__((ext_vector_type(8)));
typedef float f32x16 __attribute__((ext_vector_type(16)));

__device__ __forceinline__ uint16_t f2bf(float f) {
    uint32_t u = __float_as_uint(f);
    uint32_t r = (u + 0x7fffu + ((u >> 16) & 1u)) >> 16;   // RTN-even
    return (uint16_t)r;
}

// ---------------------------------------------------------------------------
// Kernel 1: q = (h @ Wq)/16, k = h @ Wk, bf16 frag-major. Grid 512:
// bid = rowtile*2 + which, 32 rows per block. W half staged coalesced to LDS;
// C-tile repacked via per-wave LDS scratch -> 2 coalesced dwordx4 stores.
// Also zero-inits l_arr / c_arr / out.
// ---------------------------------------------------------------------------
__global__ __launch_bounds__(256) void proj_kernel(
        const float* __restrict__ h, const float* __restrict__ Wq,
        const float* __restrict__ Wk, uint16_t* __restrict__ qf,
        uint16_t* __restrict__ kf, float* __restrict__ l_arr,
        float* __restrict__ c_arr, float* __restrict__ out) {
    __shared__ alignas(16) uint16_t wb[256 * 128];    // 64 KB: W[:, half] bf16
    __shared__ alignas(16) uint16_t rep[4][2048];     // 16 KB: per-wave repack
    const int tid = threadIdx.x, lane = tid & 63, wave = tid >> 6;
    const int which = blockIdx.x & 1;
    const int rt = blockIdx.x >> 1;                   // 0..255 (32-row tiles)

    if (blockIdx.x < 32)       l_arr[blockIdx.x * 256 + tid] = 0.0f;
    else if (blockIdx.x < 64)  c_arr[(blockIdx.x - 32) * 256 + tid] = 0.0f;
    else if (blockIdx.x == 64) out[tid] = 0.0f;

    const float* __restrict__ W = which ? Wk : Wq;
    uint16_t* __restrict__ dst = which ? kf : qf;
    const float scale = which ? 1.0f : 0.0625f;

    // A-fragments: rows rt*32..+31, full K=256 (32x32 A layout), bf16 in regs
    bf16x8 afrag[16];
    {
        const int r = rt * 32 + (lane & 31);
        const float* hp = h + (size_t)r * DIM + ((lane >> 5) * 8);
#pragma unroll
        for (int a0 = 0; a0 < 16; a0++) {
            float4 f0 = *(const float4*)(hp + a0 * 16);
            float4 f1 = *(const float4*)(hp + a0 * 16 + 4);
            u16x8 f;
            f[0] = f2bf(f0.x); f[1] = f2bf(f0.y); f[2] = f2bf(f0.z); f[3] = f2bf(f0.w);
            f[4] = f2bf(f1.x); f[5] = f2bf(f1.y); f[6] = f2bf(f1.z); f[7] = f2bf(f1.w);
            afrag[a0] = __builtin_bit_cast(bf16x8, f);
        }
    }

    for (int p = 0; p < 2; p++) {
        __syncthreads();                              // LDS reuse between phases
#pragma unroll
        for (int c = 0; c < 32; c++) {                // coalesced float4 -> bf16
            int f = c * 256 + tid;                    // float4 index, 0..8191
            int k = f >> 5, nc = (f & 31) * 4;
            float4 w4 = *(const float4*)&W[(size_t)k * DIM + p * 128 + nc];
            ushort4 b;
            b.x = f2bf(w4.x); b.y = f2bf(w4.y); b.z = f2bf(w4.z); b.w = f2bf(w4.w);
            *(ushort4*)&wb[k * 128 + nc] = b;
        }
        __syncthreads();

        f32x16 acc;
#pragma unroll
        for (int i = 0; i < 16; i++) acc[i] = 0.0f;
        const int cl = wave * 32 + (lane & 31);       // local col in [0,128)
#pragma unroll
        for (int a0 = 0; a0 < 16; a0++) {
            const int kb = a0 * 16 + (lane >> 5) * 8;
            u16x8 f;
#pragma unroll
            for (int j = 0; j < 8; j++) f[j] = wb[(kb + j) * 128 + cl];
            acc = __builtin_amdgcn_mfma_f32_32x32x16_bf16(
                afrag[a0], __builtin_bit_cast(bf16x8, f), acc, 0, 0, 0);
        }

        // repack C-tile (32 rows x 32 cols) into frag layout via wave-local LDS
        {
            const int dcl = lane & 31;                // local col 0..31
            const int a0o = dcl >> 4, hi = (dcl >> 3) & 1, j = dcl & 7;
            const int ilb = 4 * (lane >> 5);
#pragma unroll
            for (int reg = 0; reg < 16; reg++) {
                int il = ilb + (reg & 3) + 8 * (reg >> 2);
                rep[wave][(size_t)((a0o * 64) + il + 32 * hi) * 8 + j] =
                    f2bf(acc[reg] * scale);
            }
            // wave-local RAW; compiler inserts lgkmcnt wait
            const uint4* rp = (const uint4*)&rep[wave][0];
            uint4* gp = (uint4*)(dst + (size_t)rt * 8192 +
                                 (size_t)(p * 8 + wave * 2) * 512);
            gp[lane * 2]     = rp[lane * 2];
            gp[lane * 2 + 1] = rp[lane * 2 + 1];
        }
    }
}

// ---------------------------------------------------------------------------
// Kernels 2/3: two QK^T passes, barrier-free, LDS-free B path.
// MODE 0: row sums l_i. MODE 1: weighted column sums c_j.
// Grid 512 = 32 rowblocks(256 rows) x 16 colchunks(512 cols), 2 blocks/CU.
// Wave: 2 rowtiles resident (128 VGPR q), B streamed from global (L2-hot)
// through ping-pong 4-fragment quarter-buffers.
// ---------------------------------------------------------------------------
template <int MODE>
__global__ __launch_bounds__(256, 2) void qk_pass(
        const uint16_t* __restrict__ qf, const uint16_t* __restrict__ kf,
        float* __restrict__ l_arr, float* __restrict__ c_arr) {
    __shared__ float c_lds[512];                      // MODE 1 only (2 KB)
    const int tid = threadIdx.x, lane = tid & 63, wave = tid >> 6;
    const int bid = blockIdx.x;
    const int cc = ((bid & 7) << 1) | ((bid >> 3) & 1);   // 2 k-slices per XCD
    const int rb = bid >> 4;                          // 0..31
    const int t0 = rb * 8 + wave * 2;                 // rowtiles t0, t0+1

    // resident q fragments: 2 rowtiles x 16 k-chunks = 128 regs
    const uint4* qp = (const uint4*)qf;
    bf16x8 q0[16], q1[16];
#pragma unroll
    for (int a0 = 0; a0 < 16; a0++) {
        q0[a0] = __builtin_bit_cast(bf16x8, qp[(size_t)t0 * 1024 + a0 * 64 + lane]);
        q1[a0] = __builtin_bit_cast(bf16x8, qp[(size_t)(t0 + 1) * 1024 + a0 * 64 + lane]);
    }

    float rs0[16], rs1[16];   // MODE 0 row-sum partials
    float rr0[16], rr1[16];   // MODE 1: 1/(N*l_i)
    if (MODE == 0) {
#pragma unroll
        for (int r = 0; r < 16; r++) { rs0[r] = 0.0f; rs1[r] = 0.0f; }
    } else {
#pragma unroll
        for (int r = 0; r < 16; r++) {
            int ro = (r & 3) + 8 * (r >> 2) + 4 * (lane >> 5);
            rr0[r] = 1.0f / (8192.0f * l_arr[t0 * 32 + ro]);
            rr1[r] = 1.0f / (8192.0f * l_arr[(t0 + 1) * 32 + ro]);
        }
        for (int i = tid; i < 512; i += 256) c_lds[i] = 0.0f;
        __syncthreads();
    }

    const uint4* kp = (const uint4*)kf;
    bf16x8 b[2][4];                                   // ping-pong quarter-buffers
    {   // prime quarter 0 of tile 0
        const uint4* kt = kp + (size_t)(cc * 16) * 1024;
#pragma unroll
        for (int i = 0; i < 4; i++)
            b[0][i] = __builtin_bit_cast(bf16x8, kt[i * 64 + lane]);
    }

    f32x16 acc0, acc1;
#pragma unroll
    for (int i = 0; i < 16; i++) { acc0[i] = 0.0f; acc1[i] = 0.0f; }

    for (int s = 0; s < 16; s++) {
        const uint4* kt  = kp + (size_t)(cc * 16 + s) * 1024;
        const uint4* ktn = kt + 1024;
#pragma unroll
        for (int qd = 0; qd < 4; qd++) {
            const int cur = qd & 1, nxt = cur ^ 1;
            if (qd < 3) {                             // next quarter, this tile
#pragma unroll
                for (int i = 0; i < 4; i++)
                    b[nxt][i] = __builtin_bit_cast(bf16x8,
                        kt[((qd + 1) * 4 + i) * 64 + lane]);
            } else if (s < 15) {                      // quarter 0, next tile
#pragma unroll
                for (int i = 0; i < 4; i++)
                    b[nxt][i] = __builtin_bit_cast(bf16x8, ktn[i * 64 + lane]);
            }
#pragma unroll
            for (int i = 0; i < 4; i++) {
                acc0 = __builtin_amdgcn_mfma_f32_32x32x16_bf16(
                    q0[qd * 4 + i], b[cur][i], acc0, 0, 0, 0);
                acc1 = __builtin_amdgcn_mfma_f32_32x32x16_bf16(
                    q1[qd * 4 + i], b[cur][i], acc1, 0, 0, 0);
            }
        }
        // epilogue for tile s (next tile's quarter-0 loads are in flight)
        if (MODE == 0) {
#pragma unroll
            for (int r = 0; r < 16; r++) {
                rs0[r] += __expf(acc0[r]);  acc0[r] = 0.0f;
                rs1[r] += __expf(acc1[r]);  acc1[r] = 0.0f;
            }
        } else {
            float sv = 0.0f;
#pragma unroll
            for (int r = 0; r < 16; r++) {
                sv += __expf(acc0[r]) * rr0[r];  acc0[r] = 0.0f;
                sv += __expf(acc1[r]) * rr1[r];  acc1[r] = 0.0f;
            }
            sv += __shfl_xor(sv, 32);                 // fold row halves per col
            if (lane < 32) atomicAdd(&c_lds[s * 32 + lane], sv);
        }
    }

    if (MODE == 0) {
#pragma unroll
        for (int r = 0; r < 16; r++) {
            int ro = (r & 3) + 8 * (r >> 2) + 4 * (lane >> 5);
            float v0 = rs0[r], v1 = rs1[r];
            v0 += __shfl_xor(v0, 1);  v0 += __shfl_xor(v0, 2);
            v0 += __shfl_xor(v0, 4);  v0 += __shfl_xor(v0, 8);
            v0 += __shfl_xor(v0, 16);
            v1 += __shfl_xor(v1, 1);  v1 += __shfl_xor(v1, 2);
            v1 += __shfl_xor(v1, 4);  v1 += __shfl_xor(v1, 8);
            v1 += __shfl_xor(v1, 16);
            if ((lane & 31) == 0) {
                atomicAdd(&l_arr[t0 * 32 + ro], v0);
                atomicAdd(&l_arr[(t0 + 1) * 32 + ro], v1);
            }
        }
    } else {
        __syncthreads();
        for (int i = tid; i < 512; i += 256) atomicAdd(&c_arr[cc * 512 + i], c_lds[i]);
    }
}

// ---------------------------------------------------------------------------
// Kernel 4: x = c @ h. 128 blocks x 64 rows; coalesced h reads.
// ---------------------------------------------------------------------------
__global__ __launch_bounds__(256) void finish_kernel(
        const float* __restrict__ h, const float* __restrict__ c_arr,
        float* __restrict__ out) {
    const int d = threadIdx.x;
    const int j0 = blockIdx.x * 64;
    float acc = 0.0f;
    for (int j = j0; j < j0 + 64; j++) acc += c_arr[j] * h[(size_t)j * DIM + d];
    atomicAdd(&out[d], acc);
}

// ---------------------------------------------------------------------------
extern "C" void kernel_launch(void* const* d_in, const int* in_sizes, int n_in,
                              void* d_out, int out_size, void* d_ws, size_t ws_size,
                              hipStream_t stream) {
    const float* h  = (const float*)d_in[0];
    const float* Wq = (const float*)d_in[1];
    const float* Wk = (const float*)d_in[2];

    uint16_t* qf = (uint16_t*)d_ws;
    uint16_t* kf = qf + (size_t)N_ROWS * DIM;
    float* l_arr = (float*)((char*)d_ws + (size_t)8 * 1024 * 1024);
    float* c_arr = l_arr + N_ROWS;
    float* out = (float*)d_out;

    proj_kernel<<<512, 256, 0, stream>>>(h, Wq, Wk, qf, kf, l_arr, c_arr, out);
    qk_pass<0><<<512, 256, 0, stream>>>(qf, kf, l_arr, c_arr);
    qk_pass<1><<<512, 256, 0, stream>>>(qf, kf, l_arr, c_arr);
    finish_kernel<<<128, 256, 0, stream>>>(h, c_arr, out);
}